// Round 7
// baseline (4643.455 us; speedup 1.0000x reference)
//
#include <hip/hip_runtime.h>
#include <hip/hip_bf16.h>
#include <stdint.h>

// Residual VQ: B=16,E=64,H=64,W=64; K=1024 codes, NC=8 stages.
// BIT-EXACT fp32 emulation of the (XLA-CPU) fp32 reference:
//   S_n  = sequential fp32 sum of r[e]*r[e]           (mul,add each RNE-rounded)
//   t_nk = sequential fp32 FMA dot over e ascending   (Eigen gebp semantics)
//   n_k  = sequential fp32 sum of c[e]*c[e]
//   d    = fp32(fp32(S - fp32(2*t)) + n);  argmin first-min
//   res  = fp32(res - q);  quant = fp32 sum of q over stages (ascending)
// If the golden follows these semantics, output is BIT-IDENTICAL (absmax 0).
// All critical ops via __fmul_rn/__fadd_rn/__fsub_rn/__fmaf_rn to block
// compiler contraction/reassociation.

#define NC     8
#define KCB    1024
#define ED     64
#define NTOK   65536
#define NTHREADS 256    // 1 thread = 1 token; 256 tokens/block
#define CHUNK  128      // codes staged in LDS per iteration
#define NCHUNK (KCB / CHUNK)

typedef __attribute__((ext_vector_type(4))) float f32x4;

// ||c||^2 per (stage,code): sequential fp32, e ascending (reduce emulation).
__global__ void rvq_norm32(const float* __restrict__ cb, float* __restrict__ ncb) {
  int code = blockIdx.x * blockDim.x + threadIdx.x;   // 0..8191
  const float* row = cb + (size_t)code * ED;
  float acc = 0.0f;
#pragma unroll
  for (int e = 0; e < ED; ++e)
    acc = __fadd_rn(acc, __fmul_rn(row[e], row[e]));
  ncb[code] = acc;
}

__launch_bounds__(NTHREADS, 1)
__global__ void rvq_fp32emu(const float* __restrict__ emb, const float* __restrict__ cb,
                            const float* __restrict__ ncb, float* __restrict__ out) {
  __shared__ float lrow[CHUNK * ED];   // 32 KB: chunk of codebook rows
  __shared__ float lnn[CHUNK];         // fp32 norms

  const int tid = threadIdx.x;
  const int tok = blockIdx.x * NTHREADS + tid;
  const size_t tb = (size_t)(tok >> 12) * 262144 + (size_t)(tok & 4095);

  float r[ED], qa[ED];
#pragma unroll
  for (int e = 0; e < ED; ++e) {
    r[e]  = emb[tb + (size_t)e * 4096];
    qa[e] = 0.0f;
  }

  for (int s = 0; s < NC; ++s) {
    // S = sequential fp32 sum of squares, e ascending.
    float S = 0.0f;
#pragma unroll
    for (int e = 0; e < ED; ++e)
      S = __fadd_rn(S, __fmul_rn(r[e], r[e]));

    float best = 3.402823466e+38f;
    int   bi   = 0;

    for (int ch = 0; ch < NCHUNK; ++ch) {
      __syncthreads();   // protect LDS from previous chunk's readers
      const float* src = cb + ((size_t)s * KCB + (size_t)ch * CHUNK) * ED;
#pragma unroll
      for (int v = 0; v < 8; ++v) {
        int idx = v * NTHREADS + tid;  // 2048 f32x4 slots
        *(f32x4*)(lrow + idx * 4) = *(const f32x4*)(src + idx * 4);
      }
      if (tid < CHUNK) lnn[tid] = ncb[(size_t)s * KCB + (size_t)ch * CHUNK + tid];
      __syncthreads();

#pragma unroll 2
      for (int c = 0; c < CHUNK; ++c) {
        const float* row = lrow + c * ED;   // wave-uniform -> LDS broadcast
        // t = sequential fp32 FMA dot, e ascending (Eigen gebp order).
        float t = 0.0f;
#pragma unroll
        for (int e = 0; e < ED; ++e)
          t = __fmaf_rn(r[e], row[e], t);
        float d = __fadd_rn(__fsub_rn(S, __fmul_rn(2.0f, t)), lnn[c]);
        int k = ch * CHUNK + c;
        bool cnew = d < best;               // strict <: first-min tie-break
        best = cnew ? d : best;
        bi   = cnew ? k : bi;
      }
    }

    // Gather chosen row; fp32 residual update + fp32 quant accumulation.
    const float* crow = cb + ((size_t)s * KCB + bi) * ED;
#pragma unroll
    for (int e = 0; e < ED; ++e) {
      float q = crow[e];
      r[e]  = __fsub_rn(r[e], q);
      qa[e] = __fadd_rn(qa[e], q);
    }
  }

#pragma unroll
  for (int e = 0; e < ED; ++e)
    out[tb + (size_t)e * 4096] = qa[e];
}

extern "C" void kernel_launch(void* const* d_in, const int* in_sizes, int n_in,
                              void* d_out, int out_size, void* d_ws, size_t ws_size,
                              hipStream_t stream) {
  const float* emb = (const float*)d_in[0];   // [16,64,64,64] fp32
  const float* cb  = (const float*)d_in[1];   // [8,1024,64]   fp32
  float* out = (float*)d_out;
  float* ncb = (float*)d_ws;                  // 32 KB

  rvq_norm32<<<(NC * KCB) / NTHREADS, NTHREADS, 0, stream>>>(cb, ncb);
  rvq_fp32emu<<<NTOK / NTHREADS, NTHREADS, 0, stream>>>(emb, cb, ncb, out);
}

// Round 10
// 1215.633 us; speedup vs baseline: 3.8198x; 3.8198x over previous
//
#include <hip/hip_runtime.h>
#include <hip/hip_bf16.h>
#include <stdint.h>

// Residual VQ: B=16,E=64,H=64,W=64; K=1024 codes, NC=8 stages.
// BIT-EXACT fp32 emulation of the reference trajectory (proven round 7):
//   S  = sequential fp32 sum r[e]*r[e], e ascending
//   t  = sequential fp32 FMA dot over e ascending
//   d  = fp32(fp32(S - fp32(2*t)) + n);  argmin first-min
//   r -= q (fp32); out[e] = fp32 sum of q_s[e], s ascending
// Optimization vs round 7 (4725us, VALUBusy 21%, 1 wave/SIMD):
//   * 4 threads/token (codes 4-way interleaved; each code's chain whole in
//     one thread; (d,idx)-lex merge across subs == global first-min)
//   * 4 independent code-chains per thread (ILP)
//   * ds_read_b128 rows from pitch-68 LDS (subs' rows 4 banks apart:
//     conflict-free 16-lane broadcasts)
//   * stage-winner history in LDS; quant re-gathered at end (bit-exact order)

#define NC     8
#define KCB    1024
#define ED     64
#define NTOK   65536
#define NTHREADS 256
#define TPT    4                      // threads per token
#define TOKPB  (NTHREADS / TPT)       // 64 tokens per block
#define CHUNK  128                    // codes staged per LDS chunk
#define NCHUNK (KCB / CHUNK)
#define PITCH  68                     // lrow pitch in floats (bank-stagger pad)

typedef __attribute__((ext_vector_type(4))) float f32x4;

// ||c||^2 per (stage,code): sequential fp32, e ascending (bit-exact semantics).
__global__ void rvq_norm32(const float* __restrict__ cb, float* __restrict__ ncb) {
  int code = blockIdx.x * blockDim.x + threadIdx.x;   // 0..8191
  const float* row = cb + (size_t)code * ED;
  float acc = 0.0f;
#pragma unroll
  for (int e = 0; e < ED; ++e)
    acc = __fadd_rn(acc, __fmul_rn(row[e], row[e]));
  ncb[code] = acc;
}

__launch_bounds__(NTHREADS, 4)
__global__ void rvq_fp32emu4(const float* __restrict__ emb, const float* __restrict__ cb,
                             const float* __restrict__ ncb, float* __restrict__ out) {
  __shared__ float lrow[CHUNK * PITCH];   // 34.0 KB padded codebook chunk
  __shared__ float lnn[CHUNK];            // fp32 norms
  __shared__ int   lbh[TOKPB][NC];        // per-token winning code history

  const int tid  = threadIdx.x;
  const int sub  = tid & 3;               // code-partition lane within token
  const int tokl = tid >> 2;              // token slot in block
  const int tok  = blockIdx.x * TOKPB + tokl;
  const size_t tb = (size_t)(tok >> 12) * 262144 + (size_t)(tok & 4095);

  // Full residual per thread (all 4 subs redundant -> identical trajectories).
  float r[ED];
#pragma unroll
  for (int e = 0; e < ED; ++e) r[e] = emb[tb + (size_t)e * 4096];

  for (int s = 0; s < NC; ++s) {
    // S = sequential fp32 sum of squares, e ascending.
    float S = 0.0f;
#pragma unroll
    for (int e = 0; e < ED; ++e)
      S = __fadd_rn(S, __fmul_rn(r[e], r[e]));

    float best = 3.402823466e+38f;
    int   bi   = 0;

    for (int ch = 0; ch < NCHUNK; ++ch) {
      __syncthreads();   // protect LDS from previous chunk's readers
      const float* src = cb + ((size_t)s * KCB + (size_t)ch * CHUNK) * ED;
#pragma unroll
      for (int v = 0; v < 8; ++v) {
        int slot = v * NTHREADS + tid;          // 2048 f32x4 tiles
        int c = slot >> 4, e4 = slot & 15;
        *(f32x4*)(lrow + c * PITCH + e4 * 4) = *(const f32x4*)(src + c * 64 + e4 * 4);
      }
      if (tid < CHUNK) lnn[tid] = ncb[(size_t)s * KCB + (size_t)ch * CHUNK + tid];
      __syncthreads();

      // This thread's codes: c = 16*u + 4*j + sub (u=0..7, j=0..3), ascending.
      for (int u = 0; u < 8; ++u) {
        const int cbase = 16 * u + sub;
        const float* rp0 = lrow + (cbase)      * PITCH;
        const float* rp1 = lrow + (cbase + 4)  * PITCH;
        const float* rp2 = lrow + (cbase + 8)  * PITCH;
        const float* rp3 = lrow + (cbase + 12) * PITCH;
        float a0 = 0.0f, a1 = 0.0f, a2 = 0.0f, a3 = 0.0f;
#pragma unroll
        for (int e4 = 0; e4 < 16; ++e4) {
          f32x4 w0 = *(const f32x4*)(rp0 + e4 * 4);
          f32x4 w1 = *(const f32x4*)(rp1 + e4 * 4);
          f32x4 w2 = *(const f32x4*)(rp2 + e4 * 4);
          f32x4 w3 = *(const f32x4*)(rp3 + e4 * 4);
#pragma unroll
          for (int j = 0; j < 4; ++j) {
            float re = r[e4 * 4 + j];
            a0 = __fmaf_rn(re, w0[j], a0);
            a1 = __fmaf_rn(re, w1[j], a1);
            a2 = __fmaf_rn(re, w2[j], a2);
            a3 = __fmaf_rn(re, w3[j], a3);
          }
        }
        float d0 = __fadd_rn(__fsub_rn(S, __fmul_rn(2.0f, a0)), lnn[cbase]);
        float d1 = __fadd_rn(__fsub_rn(S, __fmul_rn(2.0f, a1)), lnn[cbase + 4]);
        float d2 = __fadd_rn(__fsub_rn(S, __fmul_rn(2.0f, a2)), lnn[cbase + 8]);
        float d3 = __fadd_rn(__fsub_rn(S, __fmul_rn(2.0f, a3)), lnn[cbase + 12]);
        int cg = ch * CHUNK + cbase;
        if (d0 < best) { best = d0; bi = cg; }       // strict <: first-min
        if (d1 < best) { best = d1; bi = cg + 4; }
        if (d2 < best) { best = d2; bi = cg + 8; }
        if (d3 < best) { best = d3; bi = cg + 12; }
      }
    }

    // Merge across the 4 subs of this token (lanes differ in bits 0..1).
    // (d, idx) lexicographic min == global first-min over all 1024 codes.
#pragma unroll
    for (int mask = 1; mask <= 2; mask <<= 1) {
      float ob = __shfl_xor(best, mask, 64);
      int   oi = __shfl_xor(bi, mask, 64);
      if (ob < best || (ob == best && oi < bi)) { best = ob; bi = oi; }
    }
    if (sub == 0) lbh[tokl][s] = bi;

    // fp32 residual update with the winning row (gather from L2-hot codebook).
    const float* crow = cb + ((size_t)s * KCB + bi) * ED;
#pragma unroll
    for (int e4 = 0; e4 < 16; ++e4) {
      f32x4 q = *(const f32x4*)(crow + e4 * 4);
#pragma unroll
      for (int j = 0; j < 4; ++j)
        r[e4 * 4 + j] = __fsub_rn(r[e4 * 4 + j], q[j]);
    }
  }
  __syncthreads();

  // quant[e] = fp32 sum of q_s[e], s ascending (bit-exact re-gather).
  // Each sub handles 16 dims: e = sub*16 + 4*j4 + j.
#pragma unroll
  for (int j4 = 0; j4 < 4; ++j4) {
    int e0 = sub * 16 + j4 * 4;
    f32x4 qa = {0.0f, 0.0f, 0.0f, 0.0f};
#pragma unroll
    for (int s = 0; s < NC; ++s) {
      const float* crow = cb + ((size_t)s * KCB + lbh[tokl][s]) * ED + e0;
      f32x4 q = *(const f32x4*)crow;
#pragma unroll
      for (int j = 0; j < 4; ++j) qa[j] = __fadd_rn(qa[j], q[j]);
    }
#pragma unroll
    for (int j = 0; j < 4; ++j)
      out[tb + (size_t)(e0 + j) * 4096] = qa[j];
  }
}

extern "C" void kernel_launch(void* const* d_in, const int* in_sizes, int n_in,
                              void* d_out, int out_size, void* d_ws, size_t ws_size,
                              hipStream_t stream) {
  const float* emb = (const float*)d_in[0];   // [16,64,64,64] fp32
  const float* cb  = (const float*)d_in[1];   // [8,1024,64]   fp32
  float* out = (float*)d_out;
  float* ncb = (float*)d_ws;                  // 32 KB

  rvq_norm32<<<(NC * KCB) / NTHREADS, NTHREADS, 0, stream>>>(cb, ncb);
  rvq_fp32emu4<<<NTOK / TOKPB, NTHREADS, 0, stream>>>(emb, cb, ncb, out);
}